// Round 1
// 498.196 us; speedup vs baseline: 1.6549x; 1.6549x over previous
//
#include <hip/hip_runtime.h>
#include <hip/hip_bf16.h>

#define D 128

typedef unsigned int uint;
typedef unsigned short ushort;
typedef __attribute__((ext_vector_type(8))) short short8;
typedef __attribute__((ext_vector_type(4))) float f32x4;

// unpack a bf16x2 (as uint) into two floats: x = low half, y = high half
static __device__ __forceinline__ float2 bf16x2(uint u) {
  float2 r;
  r.x = __uint_as_float(u << 16);
  r.y = __uint_as_float(u & 0xffff0000u);
  return r;
}

static __device__ __forceinline__ uint pack_bf16x2(float a, float b) {
  __hip_bfloat162 o;
  o.x = __float2bfloat16(a);
  o.y = __float2bfloat16(b);
  return *reinterpret_cast<uint*>(&o);
}

static __device__ __forceinline__ ushort f2bf(float f) {
  __hip_bfloat16 h = __float2bfloat16(f);
  return *reinterpret_cast<ushort*>(&h);
}
static __device__ __forceinline__ float bf2f(ushort u) {
  return __uint_as_float(((uint)u) << 16);
}

// ---------------------------------------------------------------------------
// Detect input dtype (bf16 vs fp32 storage). flag=1 means fp32.
// ---------------------------------------------------------------------------
__global__ void detect_kernel(const uint* __restrict__ x, int n_words,
                              int* __restrict__ flag) {
  __shared__ float smax[256];
  float m = 0.f;
  for (int i = threadIdx.x; i < n_words; i += 256) {
    float2 v = bf16x2(x[i]);
    float a = fabsf(v.x), b = fabsf(v.y);
    if (!(a <= 1e30f)) a = 1e30f;
    if (!(b <= 1e30f)) b = 1e30f;
    m = fmaxf(m, fmaxf(a, b));
  }
  smax[threadIdx.x] = m;
  __syncthreads();
  for (int s = 128; s > 0; s >>= 1) {
    if (threadIdx.x < s)
      smax[threadIdx.x] = fmaxf(smax[threadIdx.x], smax[threadIdx.x + s]);
    __syncthreads();
  }
  if (threadIdx.x == 0) *flag = (smax[0] > 1e6f) ? 1 : 0;
}

// ---------------------------------------------------------------------------
// Histogram of edge destinations: deg (PPI col), cnt (DTI prot)
// ---------------------------------------------------------------------------
__global__ void count_kernel(const int* __restrict__ ppi_col,
                             const int* __restrict__ dti_prot,
                             int* __restrict__ deg, int* __restrict__ cnt,
                             int e_ppi, int e_dti, int n_prot) {
  int i = blockIdx.x * blockDim.x + threadIdx.x;
  if (i < e_ppi) {
    int c = ppi_col[i];
    if ((unsigned)c < (unsigned)n_prot) atomicAdd(&deg[c], 1);
  } else if (i < e_ppi + e_dti) {
    int c = dti_prot[i - e_ppi];
    if ((unsigned)c < (unsigned)n_prot) atomicAdd(&cnt[c], 1);
  }
}

// ---------------------------------------------------------------------------
// Per-node normalizers + per-scan-block sums (fused)
// ---------------------------------------------------------------------------
__global__ void block_sum_kernel(const int* __restrict__ deg,
                                 const int* __restrict__ cnt, int n,
                                 float* __restrict__ dinv,
                                 float* __restrict__ invcnt,
                                 int* __restrict__ bsum) {
  __shared__ int sh[256];
  int i = blockIdx.x * 256 + threadIdx.x;
  int t = 0;
  if (i < n) {
    int d = deg[i], c = cnt[i];
    dinv[i] = rsqrtf((float)(d + 1));  // +1 self-loop
    invcnt[i] = 1.0f / fmaxf((float)c, 1.0f);
    t = d + c;
  }
  sh[threadIdx.x] = t;
  __syncthreads();
  for (int s = 128; s > 0; s >>= 1) {
    if (threadIdx.x < s) sh[threadIdx.x] += sh[threadIdx.x + s];
    __syncthreads();
  }
  if (threadIdx.x == 0) bsum[blockIdx.x] = sh[0];
}

// single block: in-place exclusive scan of bsum[0..nb)
__global__ void scan_bsums_kernel(int* __restrict__ bsum, int nb) {
  __shared__ int sh[1024];
  __shared__ int carry;
  int tid = threadIdx.x;
  if (tid == 0) carry = 0;
  __syncthreads();
  for (int base = 0; base < nb; base += 1024) {
    int i = base + tid;
    int v = (i < nb) ? bsum[i] : 0;
    sh[tid] = v;
    __syncthreads();
    for (int ofs = 1; ofs < 1024; ofs <<= 1) {
      int t = (tid >= ofs) ? sh[tid - ofs] : 0;
      __syncthreads();
      sh[tid] += t;
      __syncthreads();
    }
    if (i < nb) bsum[i] = carry + sh[tid] - v;  // exclusive
    int total = sh[1023];
    __syncthreads();
    if (tid == 0) carry += total;
    __syncthreads();
  }
}

__global__ void scan_final_kernel(const int* __restrict__ deg,
                                  const int* __restrict__ cnt,
                                  const int* __restrict__ bbase,
                                  int* __restrict__ offsets, int n) {
  __shared__ int sh[256];
  int tid = threadIdx.x;
  int i = blockIdx.x * 256 + tid;
  int v = (i < n) ? deg[i] + cnt[i] : 0;
  sh[tid] = v;
  __syncthreads();
  for (int ofs = 1; ofs < 256; ofs <<= 1) {
    int t = (tid >= ofs) ? sh[tid - ofs] : 0;
    __syncthreads();
    sh[tid] += t;
    __syncthreads();
  }
  if (i < n) {
    int excl = bbase[blockIdx.x] + sh[tid] - v;
    offsets[i] = excl;
    if (i == n - 1) offsets[n] = excl + v;
  }
}

// ---------------------------------------------------------------------------
// Fill CSR, segmented per node: [offsets[d], offsets[d]+deg[d]) = PPI sources,
// [offsets[d]+deg[d], offsets[d+1]) = DTI drug sources.
// ---------------------------------------------------------------------------
__global__ void fill_kernel(const int* __restrict__ ppi_row,
                            const int* __restrict__ ppi_col,
                            const int* __restrict__ dti_drug,
                            const int* __restrict__ dti_prot,
                            const int* __restrict__ offsets,
                            const int* __restrict__ deg,
                            int* __restrict__ fposp, int* __restrict__ fposd,
                            uint* __restrict__ csr, int e_ppi, int e_dti,
                            int n_prot) {
  int i = blockIdx.x * blockDim.x + threadIdx.x;
  if (i < e_ppi) {
    int dst = ppi_col[i];
    if ((unsigned)dst >= (unsigned)n_prot) return;
    int pos = offsets[dst] + atomicAdd(&fposp[dst], 1);
    csr[pos] = (uint)ppi_row[i];
  } else if (i < e_ppi + e_dti) {
    int j = i - e_ppi;
    int dst = dti_prot[j];
    if ((unsigned)dst >= (unsigned)n_prot) return;
    int pos = offsets[dst] + deg[dst] + atomicAdd(&fposd[dst], 1);
    csr[pos] = (uint)dti_drug[j];
  }
}

// ---------------------------------------------------------------------------
// MFMA dual-output protein GEMM, 512 threads = 8 waves, 64 rows per iter.
//   g = x_prot[row] @ W_gcn  -> xw2[row] = bf16(g * dinv[row])
//   outx3[row] = x_prot[row] @ W_pr + (b_gcn+b_pr+1e-6) + dinv^2 * g
// fp32 x handled exactly via hi/lo bf16 split (x = hi + lo), so precision
// matches the previous fp32-x * bf16-W kernel.
// Each wave owns one 16-col slice; B fragments live in VGPRs for the whole
// block. A is staged to LDS in MFMA fragment-linear layout (ds_read_b128).
// ---------------------------------------------------------------------------
__global__ __launch_bounds__(512) void gemm_prot_mfma(
    const void* __restrict__ X, const void* __restrict__ Wg,
    const void* __restrict__ Wp, const void* __restrict__ bg,
    const void* __restrict__ bp, const float* __restrict__ dinv,
    uint* __restrict__ xw2, void* __restrict__ outx3,
    const int* __restrict__ flag, int M) {
  __shared__ uint4 aF[4][4][2][64];  // [rowgrp][ktile][hi/lo][lane] : 32 KB
  __shared__ ushort xwl[64][128];    // transpose buffer for xw2 : 16 KB
  const int isf = *flag;
  const int tid = threadIdx.x;
  const int wv = tid >> 6, lane = tid & 63;
  const int cl = lane & 15, kg = lane >> 4;
  const int c = wv * 16 + cl;  // this wave's output column (0..127)

  // ---- B fragments (both matrices), kept in VGPRs for the whole block ----
  // frag element j = W[kt*32 + 8*kg + j][c]
  short8 bG[4], bP[4];
#pragma unroll
  for (int kt = 0; kt < 4; ++kt) {
    int k0 = kt * 32 + 8 * kg;
    short8 fg, fp;
    if (isf) {
      const float* WgF = (const float*)Wg;
      const float* WpF = (const float*)Wp;
#pragma unroll
      for (int j = 0; j < 8; ++j) {
        fg[j] = (short)f2bf(WgF[(k0 + j) * D + c]);
        fp[j] = (short)f2bf(WpF[(k0 + j) * D + c]);
      }
    } else {
      const ushort* WgH = (const ushort*)Wg;
      const ushort* WpH = (const ushort*)Wp;
#pragma unroll
      for (int j = 0; j < 8; ++j) {
        fg[j] = (short)WgH[(k0 + j) * D + c];
        fp[j] = (short)WpH[(k0 + j) * D + c];
      }
    }
    bG[kt] = fg;
    bP[kt] = fp;
  }
  float btc;
  {
    float a = isf ? ((const float*)bg)[c] : bf2f(((const ushort*)bg)[c]);
    float b = isf ? ((const float*)bp)[c] : bf2f(((const ushort*)bp)[c]);
    btc = a + b + 1e-6f;
  }

  for (int row0 = blockIdx.x * 64; row0 < M; row0 += gridDim.x * 64) {
    // ---- stage 64 rows of X into LDS as bf16 hi/lo fragments ----
    for (int u = tid; u < 1024; u += 512) {
      int row = u >> 4, kc = u & 15;  // row 0..63, 8-elem k-chunk 0..15
      int grow = row0 + row;
      uint4 hi = make_uint4(0, 0, 0, 0), lo = make_uint4(0, 0, 0, 0);
      if (isf) {
        if (grow < M) {
          const float4* Xf = (const float4*)X;
          float4 v0 = Xf[(size_t)grow * 32 + kc * 2];
          float4 v1 = Xf[(size_t)grow * 32 + kc * 2 + 1];
          float v[8] = {v0.x, v0.y, v0.z, v0.w, v1.x, v1.y, v1.z, v1.w};
          uint hw[4], lw[4];
#pragma unroll
          for (int j = 0; j < 4; ++j) {
            ushort h0 = f2bf(v[2 * j]), h1 = f2bf(v[2 * j + 1]);
            ushort l0 = f2bf(v[2 * j] - bf2f(h0));
            ushort l1 = f2bf(v[2 * j + 1] - bf2f(h1));
            hw[j] = (uint)h0 | ((uint)h1 << 16);
            lw[j] = (uint)l0 | ((uint)l1 << 16);
          }
          hi = make_uint4(hw[0], hw[1], hw[2], hw[3]);
          lo = make_uint4(lw[0], lw[1], lw[2], lw[3]);
        }
      } else {
        if (grow < M) hi = ((const uint4*)X)[(size_t)grow * 16 + kc];
      }
      int ln = (kc & 3) * 16 + (row & 15);
      int g = row >> 4, kt = kc >> 2;
      aF[g][kt][0][ln] = hi;
      if (isf) aF[g][kt][1][ln] = lo;
    }
    __syncthreads();

    // ---- 4 row-groups of 16 rows ----
#pragma unroll
    for (int g = 0; g < 4; ++g) {
      f32x4 accG = {0.f, 0.f, 0.f, 0.f};
      f32x4 accP = {0.f, 0.f, 0.f, 0.f};
      uint4 aH[4];
#pragma unroll
      for (int kt = 0; kt < 4; ++kt) aH[kt] = aF[g][kt][0][lane];
#pragma unroll
      for (int kt = 0; kt < 4; ++kt) {
        short8 a = __builtin_bit_cast(short8, aH[kt]);
        accG = __builtin_amdgcn_mfma_f32_16x16x32_bf16(a, bG[kt], accG, 0, 0, 0);
        accP = __builtin_amdgcn_mfma_f32_16x16x32_bf16(a, bP[kt], accP, 0, 0, 0);
      }
      if (isf) {
        uint4 aL[4];
#pragma unroll
        for (int kt = 0; kt < 4; ++kt) aL[kt] = aF[g][kt][1][lane];
#pragma unroll
        for (int kt = 0; kt < 4; ++kt) {
          short8 a = __builtin_bit_cast(short8, aL[kt]);
          accG = __builtin_amdgcn_mfma_f32_16x16x32_bf16(a, bG[kt], accG, 0, 0, 0);
          accP = __builtin_amdgcn_mfma_f32_16x16x32_bf16(a, bP[kt], accP, 0, 0, 0);
        }
      }
      // D layout: col = lane&15 (== our c), row = kg*4 + r
      int rl0 = g * 16 + kg * 4;
#pragma unroll
      for (int r = 0; r < 4; ++r) {
        int row = row0 + rl0 + r;
        if (row < M) {
          float dn = dinv[row];
          float gv = accG[r], pv = accP[r];
          xwl[rl0 + r][c] = f2bf(gv * dn);
          float ov = fmaf(gv, dn * dn, pv + btc);
          if (isf)
            ((float*)outx3)[(size_t)row * D + c] = ov;
          else
            ((ushort*)outx3)[(size_t)row * D + c] = f2bf(ov);
        }
      }
    }
    __syncthreads();

    // ---- coalesced xw2 writeout (uint4 = 8 bf16) ----
    int valid = min(64, M - row0);
    const uint4* src = (const uint4*)xwl;
    uint4* dst = (uint4*)xw2 + (size_t)row0 * 16;
    for (int u = tid; u < valid * 16; u += 512) dst[u] = src[u];
  }
}

// ---------------------------------------------------------------------------
// MFMA drug GEMM: yd2[M][64] bf16 pairs = x_drug @ W_td + b_td
// ---------------------------------------------------------------------------
__global__ __launch_bounds__(512) void gemm_drug_mfma(
    const void* __restrict__ X, const void* __restrict__ W,
    const void* __restrict__ bias, uint* __restrict__ Y2,
    const int* __restrict__ flag, int M) {
  __shared__ uint4 aF[4][4][2][64];  // 32 KB
  __shared__ ushort yl[64][128];     // 16 KB
  const int isf = *flag;
  const int tid = threadIdx.x;
  const int wv = tid >> 6, lane = tid & 63;
  const int cl = lane & 15, kg = lane >> 4;
  const int c = wv * 16 + cl;

  short8 bT[4];
#pragma unroll
  for (int kt = 0; kt < 4; ++kt) {
    int k0 = kt * 32 + 8 * kg;
    short8 ft;
    if (isf) {
      const float* Wf = (const float*)W;
#pragma unroll
      for (int j = 0; j < 8; ++j) ft[j] = (short)f2bf(Wf[(k0 + j) * D + c]);
    } else {
      const ushort* Wh = (const ushort*)W;
#pragma unroll
      for (int j = 0; j < 8; ++j) ft[j] = (short)Wh[(k0 + j) * D + c];
    }
    bT[kt] = ft;
  }
  float btc = isf ? ((const float*)bias)[c] : bf2f(((const ushort*)bias)[c]);

  for (int row0 = blockIdx.x * 64; row0 < M; row0 += gridDim.x * 64) {
    for (int u = tid; u < 1024; u += 512) {
      int row = u >> 4, kc = u & 15;
      int grow = row0 + row;
      uint4 hi = make_uint4(0, 0, 0, 0), lo = make_uint4(0, 0, 0, 0);
      if (isf) {
        if (grow < M) {
          const float4* Xf = (const float4*)X;
          float4 v0 = Xf[(size_t)grow * 32 + kc * 2];
          float4 v1 = Xf[(size_t)grow * 32 + kc * 2 + 1];
          float v[8] = {v0.x, v0.y, v0.z, v0.w, v1.x, v1.y, v1.z, v1.w};
          uint hw[4], lw[4];
#pragma unroll
          for (int j = 0; j < 4; ++j) {
            ushort h0 = f2bf(v[2 * j]), h1 = f2bf(v[2 * j + 1]);
            ushort l0 = f2bf(v[2 * j] - bf2f(h0));
            ushort l1 = f2bf(v[2 * j + 1] - bf2f(h1));
            hw[j] = (uint)h0 | ((uint)h1 << 16);
            lw[j] = (uint)l0 | ((uint)l1 << 16);
          }
          hi = make_uint4(hw[0], hw[1], hw[2], hw[3]);
          lo = make_uint4(lw[0], lw[1], lw[2], lw[3]);
        }
      } else {
        if (grow < M) hi = ((const uint4*)X)[(size_t)grow * 16 + kc];
      }
      int ln = (kc & 3) * 16 + (row & 15);
      int g = row >> 4, kt = kc >> 2;
      aF[g][kt][0][ln] = hi;
      if (isf) aF[g][kt][1][ln] = lo;
    }
    __syncthreads();

#pragma unroll
    for (int g = 0; g < 4; ++g) {
      f32x4 acc = {0.f, 0.f, 0.f, 0.f};
      uint4 aH[4];
#pragma unroll
      for (int kt = 0; kt < 4; ++kt) aH[kt] = aF[g][kt][0][lane];
#pragma unroll
      for (int kt = 0; kt < 4; ++kt) {
        short8 a = __builtin_bit_cast(short8, aH[kt]);
        acc = __builtin_amdgcn_mfma_f32_16x16x32_bf16(a, bT[kt], acc, 0, 0, 0);
      }
      if (isf) {
        uint4 aL[4];
#pragma unroll
        for (int kt = 0; kt < 4; ++kt) aL[kt] = aF[g][kt][1][lane];
#pragma unroll
        for (int kt = 0; kt < 4; ++kt) {
          short8 a = __builtin_bit_cast(short8, aL[kt]);
          acc = __builtin_amdgcn_mfma_f32_16x16x32_bf16(a, bT[kt], acc, 0, 0, 0);
        }
      }
      int rl0 = g * 16 + kg * 4;
#pragma unroll
      for (int r = 0; r < 4; ++r) {
        int row = row0 + rl0 + r;
        if (row < M) yl[rl0 + r][c] = f2bf(acc[r] + btc);
      }
    }
    __syncthreads();

    int valid = min(64, M - row0);
    const uint4* src = (const uint4*)yl;
    uint4* dst = (uint4*)Y2 + (size_t)row0 * 16;
    for (int u = tid; u < valid * 16; u += 512) dst[u] = src[u];
  }
}

// ---------------------------------------------------------------------------
// Pure gather + LayerNorm (no LDS, no GEMM). One wave per node.
//  v = dn * sum_ppi(xw2[src]) + ic * sum_dti(yd2[drug]) + x3'[node]
//  out[node] = LayerNorm(v)   (x3' read from d_out, overwritten in place)
// ---------------------------------------------------------------------------
__global__ __launch_bounds__(256) void gather_ln_kernel(
    const uint* __restrict__ xw2, const uint* __restrict__ yd2,
    const float* __restrict__ dinv, const float* __restrict__ invcnt,
    const int* __restrict__ offsets, const int* __restrict__ deg,
    const uint* __restrict__ csr, void* __restrict__ out,
    const int* __restrict__ flag, int n_prot) {
  int isf = *flag;
  int node = (blockIdx.x * 256 + threadIdx.x) >> 6;
  int j2 = threadIdx.x & 63;
  if (node >= n_prot) return;
  int s0 = offsets[node];
  int s1 = offsets[node + 1];
  int sm = s0 + deg[node];
  float dn = dinv[node], ic = invcnt[node];

  float apx = 0.f, apy = 0.f;  // PPI sum (rows pre-scaled by dinv[src])
  for (int base = s0; base < sm;) {
    int m = min(64, sm - base);
    uint ent = (j2 < m) ? csr[base + j2] : 0u;
    int j = 0;
    for (; j + 8 <= m; j += 8) {
      uint e0 = __shfl(ent, j), e1 = __shfl(ent, j + 1);
      uint e2 = __shfl(ent, j + 2), e3 = __shfl(ent, j + 3);
      uint e4 = __shfl(ent, j + 4), e5 = __shfl(ent, j + 5);
      uint e6 = __shfl(ent, j + 6), e7 = __shfl(ent, j + 7);
      float2 v0 = bf16x2(xw2[(size_t)e0 * 64 + j2]);
      float2 v1 = bf16x2(xw2[(size_t)e1 * 64 + j2]);
      float2 v2 = bf16x2(xw2[(size_t)e2 * 64 + j2]);
      float2 v3 = bf16x2(xw2[(size_t)e3 * 64 + j2]);
      float2 v4 = bf16x2(xw2[(size_t)e4 * 64 + j2]);
      float2 v5 = bf16x2(xw2[(size_t)e5 * 64 + j2]);
      float2 v6 = bf16x2(xw2[(size_t)e6 * 64 + j2]);
      float2 v7 = bf16x2(xw2[(size_t)e7 * 64 + j2]);
      apx += ((v0.x + v1.x) + (v2.x + v3.x)) + ((v4.x + v5.x) + (v6.x + v7.x));
      apy += ((v0.y + v1.y) + (v2.y + v3.y)) + ((v4.y + v5.y) + (v6.y + v7.y));
    }
    for (; j + 2 <= m; j += 2) {
      uint e0 = __shfl(ent, j), e1 = __shfl(ent, j + 1);
      float2 v0 = bf16x2(xw2[(size_t)e0 * 64 + j2]);
      float2 v1 = bf16x2(xw2[(size_t)e1 * 64 + j2]);
      apx += v0.x + v1.x;
      apy += v0.y + v1.y;
    }
    for (; j < m; ++j) {
      uint e = __shfl(ent, j);
      float2 v = bf16x2(xw2[(size_t)e * 64 + j2]);
      apx += v.x;
      apy += v.y;
    }
    base += m;
  }

  float adx = 0.f, ady = 0.f;  // DTI sum
  for (int base = sm; base < s1;) {
    int m = min(64, s1 - base);
    uint ent = (j2 < m) ? csr[base + j2] : 0u;
    int j = 0;
    for (; j + 8 <= m; j += 8) {
      uint e0 = __shfl(ent, j), e1 = __shfl(ent, j + 1);
      uint e2 = __shfl(ent, j + 2), e3 = __shfl(ent, j + 3);
      uint e4 = __shfl(ent, j + 4), e5 = __shfl(ent, j + 5);
      uint e6 = __shfl(ent, j + 6), e7 = __shfl(ent, j + 7);
      float2 v0 = bf16x2(yd2[(size_t)e0 * 64 + j2]);
      float2 v1 = bf16x2(yd2[(size_t)e1 * 64 + j2]);
      float2 v2 = bf16x2(yd2[(size_t)e2 * 64 + j2]);
      float2 v3 = bf16x2(yd2[(size_t)e3 * 64 + j2]);
      float2 v4 = bf16x2(yd2[(size_t)e4 * 64 + j2]);
      float2 v5 = bf16x2(yd2[(size_t)e5 * 64 + j2]);
      float2 v6 = bf16x2(yd2[(size_t)e6 * 64 + j2]);
      float2 v7 = bf16x2(yd2[(size_t)e7 * 64 + j2]);
      adx += ((v0.x + v1.x) + (v2.x + v3.x)) + ((v4.x + v5.x) + (v6.x + v7.x));
      ady += ((v0.y + v1.y) + (v2.y + v3.y)) + ((v4.y + v5.y) + (v6.y + v7.y));
    }
    for (; j + 2 <= m; j += 2) {
      uint e0 = __shfl(ent, j), e1 = __shfl(ent, j + 1);
      float2 v0 = bf16x2(yd2[(size_t)e0 * 64 + j2]);
      float2 v1 = bf16x2(yd2[(size_t)e1 * 64 + j2]);
      adx += v0.x + v1.x;
      ady += v0.y + v1.y;
    }
    for (; j < m; ++j) {
      uint e = __shfl(ent, j);
      float2 v = bf16x2(yd2[(size_t)e * 64 + j2]);
      adx += v.x;
      ady += v.y;
    }
    base += m;
  }

  float2 x3v;
  if (isf)
    x3v = ((const float2*)out)[(size_t)node * 64 + j2];
  else
    x3v = bf16x2(((const uint*)out)[(size_t)node * 64 + j2]);
  float v0 = fmaf(dn, apx, fmaf(ic, adx, x3v.x));
  float v1 = fmaf(dn, apy, fmaf(ic, ady, x3v.y));

  float s = v0 + v1, ss = v0 * v0 + v1 * v1;
  for (int off = 1; off < 64; off <<= 1) {
    s += __shfl_xor(s, off);
    ss += __shfl_xor(ss, off);
  }
  float mu = s * (1.0f / 128.0f);
  float var = ss * (1.0f / 128.0f) - mu * mu;
  float rs = rsqrtf(var + 1e-5f);
  float o0 = (v0 - mu) * rs, o1 = (v1 - mu) * rs;
  if (isf)
    ((float2*)out)[(size_t)node * 64 + j2] = make_float2(o0, o1);
  else
    ((uint*)out)[(size_t)node * 64 + j2] = pack_bf16x2(o0, o1);
}

// ---------------------------------------------------------------------------
extern "C" void kernel_launch(void* const* d_in, const int* in_sizes, int n_in,
                              void* d_out, int out_size, void* d_ws,
                              size_t ws_size, hipStream_t stream) {
  const void* x_prot = d_in[0];
  const void* x_drug = d_in[1];
  const void* W_gcn = d_in[2];
  const void* b_gcn = d_in[3];
  const void* W_td = d_in[4];
  const void* b_td = d_in[5];
  const void* W_pr = d_in[6];
  const void* b_pr = d_in[7];
  const int* ppi = (const int*)d_in[8];
  const int* dti_drug = (const int*)d_in[9];
  const int* dti_prot = (const int*)d_in[10];

  int n_prot = in_sizes[0] / D;
  int n_drug = in_sizes[1] / D;
  int e_ppi = in_sizes[8] / 2;
  int e_dti = in_sizes[9];
  int e_tot = e_ppi + e_dti;
  int nb = (n_prot + 255) / 256;

  char* ws = (char*)d_ws;
  size_t off = 0;
  auto alloc = [&](size_t bytes) {
    void* p = ws + off;
    off = (off + bytes + 255) & ~(size_t)255;
    return p;
  };
  int* flag = (int*)alloc(256);
  uint* xw2 = (uint*)alloc((size_t)n_prot * 64 * 4);  // 25.6 MB (pre-scaled)
  uint* yd2 = (uint*)alloc((size_t)n_drug * 64 * 4);  //  5.1 MB
  int* deg = (int*)alloc((size_t)n_prot * 4);
  int* cnt = (int*)alloc((size_t)n_prot * 4);
  float* dinv = (float*)alloc((size_t)n_prot * 4);
  float* invcnt = (float*)alloc((size_t)n_prot * 4);
  int* offsets = (int*)alloc((size_t)(n_prot + 1) * 4);
  int* fposp = (int*)alloc((size_t)n_prot * 4);
  int* fposd = (int*)alloc((size_t)n_prot * 4);
  int* bsum = (int*)alloc((size_t)nb * 4);
  uint* csr = (uint*)alloc((size_t)e_tot * 4);  // 9.6 MB

  if (off > ws_size) return;  // insufficient workspace: bail cleanly

  detect_kernel<<<1, 256, 0, stream>>>((const uint*)x_prot, 4096, flag);

  hipMemsetAsync(deg, 0, (size_t)n_prot * 4, stream);
  hipMemsetAsync(cnt, 0, (size_t)n_prot * 4, stream);
  hipMemsetAsync(fposp, 0, (size_t)n_prot * 4, stream);
  hipMemsetAsync(fposd, 0, (size_t)n_prot * 4, stream);

  count_kernel<<<(e_tot + 255) / 256, 256, 0, stream>>>(
      ppi + e_ppi, dti_prot, deg, cnt, e_ppi, e_dti, n_prot);

  block_sum_kernel<<<nb, 256, 0, stream>>>(deg, cnt, n_prot, dinv, invcnt,
                                           bsum);
  scan_bsums_kernel<<<1, 1024, 0, stream>>>(bsum, nb);
  scan_final_kernel<<<nb, 256, 0, stream>>>(deg, cnt, bsum, offsets, n_prot);

  fill_kernel<<<(e_tot + 255) / 256, 256, 0, stream>>>(
      ppi, ppi + e_ppi, dti_drug, dti_prot, offsets, deg, fposp, fposd, csr,
      e_ppi, e_dti, n_prot);

  int nbat_p = (n_prot + 63) / 64;
  int grid_p = nbat_p < 512 ? nbat_p : 512;
  gemm_prot_mfma<<<grid_p, 512, 0, stream>>>(x_prot, W_gcn, W_pr, b_gcn, b_pr,
                                             dinv, xw2, d_out, flag, n_prot);
  int nbat_d = (n_drug + 63) / 64;
  int grid_d = nbat_d < 512 ? nbat_d : 512;
  gemm_drug_mfma<<<grid_d, 512, 0, stream>>>(x_drug, W_td, b_td, yd2, flag,
                                             n_drug);

  gather_ln_kernel<<<(n_prot + 3) / 4, 256, 0, stream>>>(
      xw2, yd2, dinv, invcnt, offsets, deg, csr, d_out, flag, n_prot);
}

// Round 2
// 414.133 us; speedup vs baseline: 1.9908x; 1.2030x over previous
//
#include <hip/hip_runtime.h>
#include <hip/hip_bf16.h>

#define D 128
#define NPBK 256    // nodes per coarse bucket (partition/placement)
#define NBMAX 512   // max coarse buckets supported by LDS arrays
#define TILE_A 4096 // edges per partition block (256 thr x 16)

typedef unsigned int uint;
typedef unsigned short ushort;
typedef __attribute__((ext_vector_type(8))) short short8;
typedef __attribute__((ext_vector_type(4))) float f32x4;

// unpack a bf16x2 (as uint) into two floats: x = low half, y = high half
static __device__ __forceinline__ float2 bf16x2(uint u) {
  float2 r;
  r.x = __uint_as_float(u << 16);
  r.y = __uint_as_float(u & 0xffff0000u);
  return r;
}

static __device__ __forceinline__ uint pack_bf16x2(float a, float b) {
  __hip_bfloat162 o;
  o.x = __float2bfloat16(a);
  o.y = __float2bfloat16(b);
  return *reinterpret_cast<uint*>(&o);
}

static __device__ __forceinline__ ushort f2bf(float f) {
  __hip_bfloat16 h = __float2bfloat16(f);
  return *reinterpret_cast<ushort*>(&h);
}
static __device__ __forceinline__ float bf2f(ushort u) {
  return __uint_as_float(((uint)u) << 16);
}

// ---------------------------------------------------------------------------
// Detect input dtype (bf16 vs fp32 storage). flag=1 means fp32.
// ---------------------------------------------------------------------------
__global__ void detect_kernel(const uint* __restrict__ x, int n_words,
                              int* __restrict__ flag) {
  __shared__ float smax[256];
  float m = 0.f;
  for (int i = threadIdx.x; i < n_words; i += 256) {
    float2 v = bf16x2(x[i]);
    float a = fabsf(v.x), b = fabsf(v.y);
    if (!(a <= 1e30f)) a = 1e30f;
    if (!(b <= 1e30f)) b = 1e30f;
    m = fmaxf(m, fmaxf(a, b));
  }
  smax[threadIdx.x] = m;
  __syncthreads();
  for (int s = 128; s > 0; s >>= 1) {
    if (threadIdx.x < s)
      smax[threadIdx.x] = fmaxf(smax[threadIdx.x], smax[threadIdx.x + s]);
    __syncthreads();
  }
  if (threadIdx.x == 0) *flag = (smax[0] > 1e6f) ? 1 : 0;
}

// ---------------------------------------------------------------------------
// Histogram of edge destinations: deg (PPI col), cnt (DTI prot)
// ---------------------------------------------------------------------------
__global__ void count_kernel(const int* __restrict__ ppi_col,
                             const int* __restrict__ dti_prot,
                             int* __restrict__ deg, int* __restrict__ cnt,
                             int e_ppi, int e_dti, int n_prot) {
  int i = blockIdx.x * blockDim.x + threadIdx.x;
  if (i < e_ppi) {
    int c = ppi_col[i];
    if ((unsigned)c < (unsigned)n_prot) atomicAdd(&deg[c], 1);
  } else if (i < e_ppi + e_dti) {
    int c = dti_prot[i - e_ppi];
    if ((unsigned)c < (unsigned)n_prot) atomicAdd(&cnt[c], 1);
  }
}

// ---------------------------------------------------------------------------
// Per-node normalizers + per-scan-block sums (fused)
// ---------------------------------------------------------------------------
__global__ void block_sum_kernel(const int* __restrict__ deg,
                                 const int* __restrict__ cnt, int n,
                                 float* __restrict__ dinv,
                                 float* __restrict__ invcnt,
                                 int* __restrict__ bsum) {
  __shared__ int sh[256];
  int i = blockIdx.x * 256 + threadIdx.x;
  int t = 0;
  if (i < n) {
    int d = deg[i], c = cnt[i];
    dinv[i] = rsqrtf((float)(d + 1));  // +1 self-loop
    invcnt[i] = 1.0f / fmaxf((float)c, 1.0f);
    t = d + c;
  }
  sh[threadIdx.x] = t;
  __syncthreads();
  for (int s = 128; s > 0; s >>= 1) {
    if (threadIdx.x < s) sh[threadIdx.x] += sh[threadIdx.x + s];
    __syncthreads();
  }
  if (threadIdx.x == 0) bsum[blockIdx.x] = sh[0];
}

// single block: in-place exclusive scan of bsum[0..nb)
__global__ void scan_bsums_kernel(int* __restrict__ bsum, int nb) {
  __shared__ int sh[1024];
  __shared__ int carry;
  int tid = threadIdx.x;
  if (tid == 0) carry = 0;
  __syncthreads();
  for (int base = 0; base < nb; base += 1024) {
    int i = base + tid;
    int v = (i < nb) ? bsum[i] : 0;
    sh[tid] = v;
    __syncthreads();
    for (int ofs = 1; ofs < 1024; ofs <<= 1) {
      int t = (tid >= ofs) ? sh[tid - ofs] : 0;
      __syncthreads();
      sh[tid] += t;
      __syncthreads();
    }
    if (i < nb) bsum[i] = carry + sh[tid] - v;  // exclusive
    int total = sh[1023];
    __syncthreads();
    if (tid == 0) carry += total;
    __syncthreads();
  }
}

__global__ void scan_final_kernel(const int* __restrict__ deg,
                                  const int* __restrict__ cnt,
                                  const int* __restrict__ bbase,
                                  int* __restrict__ offsets, int n) {
  __shared__ int sh[256];
  int tid = threadIdx.x;
  int i = blockIdx.x * 256 + tid;
  int v = (i < n) ? deg[i] + cnt[i] : 0;
  sh[tid] = v;
  __syncthreads();
  for (int ofs = 1; ofs < 256; ofs <<= 1) {
    int t = (tid >= ofs) ? sh[tid - ofs] : 0;
    __syncthreads();
    sh[tid] += t;
    __syncthreads();
  }
  if (i < n) {
    int excl = bbase[blockIdx.x] + sh[tid] - v;
    offsets[i] = excl;
    if (i == n - 1) offsets[n] = excl + v;
  }
}

// ---------------------------------------------------------------------------
// Fallback CSR fill (only used when packing guards fail).
// ---------------------------------------------------------------------------
__global__ void fill_kernel(const int* __restrict__ ppi_row,
                            const int* __restrict__ ppi_col,
                            const int* __restrict__ dti_drug,
                            const int* __restrict__ dti_prot,
                            const int* __restrict__ offsets,
                            const int* __restrict__ deg,
                            int* __restrict__ fposp, int* __restrict__ fposd,
                            uint* __restrict__ csr, int e_ppi, int e_dti,
                            int n_prot) {
  int i = blockIdx.x * blockDim.x + threadIdx.x;
  if (i < e_ppi) {
    int dst = ppi_col[i];
    if ((unsigned)dst >= (unsigned)n_prot) return;
    int pos = offsets[dst] + atomicAdd(&fposp[dst], 1);
    csr[pos] = (uint)ppi_row[i];
  } else if (i < e_ppi + e_dti) {
    int j = i - e_ppi;
    int dst = dti_prot[j];
    if ((unsigned)dst >= (unsigned)n_prot) return;
    int pos = offsets[dst] + deg[dst] + atomicAdd(&fposd[dst], 1);
    csr[pos] = (uint)dti_drug[j];
  }
}

// ---------------------------------------------------------------------------
// bcur[b] = offsets[min(b*NPBK, n)] : coarse bucket allocation cursors
// ---------------------------------------------------------------------------
__global__ void bcur_init_kernel(const int* __restrict__ offsets,
                                 int* __restrict__ bcur, int nb, int n) {
  int b = blockIdx.x * blockDim.x + threadIdx.x;
  if (b < nb) {
    int node = b * NPBK;
    if (node > n) node = n;
    bcur[b] = offsets[node];
  }
}

// ---------------------------------------------------------------------------
// Pass A: partition edges into coarse dst-buckets (256 nodes each).
// Packed entry: src(17b) | type(1b)<<17 | (dst&255)<<18  -> one uint.
// Per-block LDS histogram -> one global atomic per (block,bucket) -> chunked
// sequential allocation, so P writes fill cache lines (~no amplification).
// ---------------------------------------------------------------------------
__global__ __launch_bounds__(256) void partition_kernel(
    const int* __restrict__ ppi_row, const int* __restrict__ ppi_col,
    const int* __restrict__ dti_drug, const int* __restrict__ dti_prot,
    int* __restrict__ bcur, uint* __restrict__ P, int e_ppi, int e_dti,
    int n_prot, int nb) {
  __shared__ int hist[NBMAX];
  __shared__ int cur[NBMAX];
  const int tid = threadIdx.x;
  const int base = blockIdx.x * TILE_A;
  const int e_tot = e_ppi + e_dti;

  for (int b = tid; b < nb; b += 256) hist[b] = 0;
  __syncthreads();

  uint sv[16];
  int dv[16];
#pragma unroll
  for (int j = 0; j < 16; ++j) {
    int i = base + j * 256 + tid;
    int d = -1;
    uint s = 0;
    if (i < e_tot) {
      int src, dst, type;
      if (i < e_ppi) {
        src = ppi_row[i];
        dst = ppi_col[i];
        type = 0;
      } else {
        int k = i - e_ppi;
        src = dti_drug[k];
        dst = dti_prot[k];
        type = 1;
      }
      if ((unsigned)dst < (unsigned)n_prot) {
        d = dst;
        s = (uint)src | ((uint)type << 17);
        atomicAdd(&hist[dst >> 8], 1);
      }
    }
    sv[j] = s;
    dv[j] = d;
  }
  __syncthreads();

  for (int b = tid; b < nb; b += 256) {
    int h = hist[b];
    cur[b] = h ? atomicAdd(&bcur[b], h) : 0;
  }
  __syncthreads();

#pragma unroll
  for (int j = 0; j < 16; ++j) {
    if (dv[j] >= 0) {
      int b = dv[j] >> 8;
      int r = atomicAdd(&cur[b], 1);
      P[r] = sv[j] | ((uint)(dv[j] & (NPBK - 1)) << 18);
    }
  }
}

// ---------------------------------------------------------------------------
// Pass B: one block per bucket. Per-node cursors in LDS (no global atomics);
// CSR writes confined to this bucket's ~24KB L2-resident window.
// ---------------------------------------------------------------------------
__global__ __launch_bounds__(256) void place_kernel(
    const uint* __restrict__ P, const int* __restrict__ offsets,
    const int* __restrict__ deg, uint* __restrict__ csr, int n_prot) {
  __shared__ int cp[NPBK];
  __shared__ int cd[NPBK];
  const int tid = threadIdx.x;
  const int node0 = blockIdx.x * NPBK;
  const int nn = min(NPBK, n_prot - node0);
  if (tid < nn) {
    int o = offsets[node0 + tid];
    cp[tid] = o;
    cd[tid] = o + deg[node0 + tid];
  }
  __syncthreads();
  const int start = offsets[node0];
  const int end = offsets[node0 + nn];
  for (int i = start + tid; i < end; i += 256) {
    uint p = P[i];
    uint src = p & 0x1ffffu;
    int nl = (int)(p >> 18);
    int pos = ((p >> 17) & 1u) ? atomicAdd(&cd[nl], 1) : atomicAdd(&cp[nl], 1);
    csr[pos] = src;
  }
}

// ---------------------------------------------------------------------------
// MFMA dual-output protein GEMM, 512 threads = 8 waves, 64 rows per iter.
//   g = x_prot[row] @ W_gcn  -> xw2[row] = bf16(g * dinv[row])
//   outx3[row] = x_prot[row] @ W_pr + (b_gcn+b_pr+1e-6) + dinv^2 * g
// fp32 x handled via hi/lo bf16 split (x = hi + lo).
// ---------------------------------------------------------------------------
__global__ __launch_bounds__(512) void gemm_prot_mfma(
    const void* __restrict__ X, const void* __restrict__ Wg,
    const void* __restrict__ Wp, const void* __restrict__ bg,
    const void* __restrict__ bp, const float* __restrict__ dinv,
    uint* __restrict__ xw2, void* __restrict__ outx3,
    const int* __restrict__ flag, int M) {
  __shared__ uint4 aF[4][4][2][64];  // [rowgrp][ktile][hi/lo][lane] : 32 KB
  __shared__ ushort xwl[64][128];    // transpose buffer for xw2 : 16 KB
  const int isf = *flag;
  const int tid = threadIdx.x;
  const int wv = tid >> 6, lane = tid & 63;
  const int cl = lane & 15, kg = lane >> 4;
  const int c = wv * 16 + cl;  // this wave's output column (0..127)

  short8 bG[4], bP[4];
#pragma unroll
  for (int kt = 0; kt < 4; ++kt) {
    int k0 = kt * 32 + 8 * kg;
    short8 fg, fp;
    if (isf) {
      const float* WgF = (const float*)Wg;
      const float* WpF = (const float*)Wp;
#pragma unroll
      for (int j = 0; j < 8; ++j) {
        fg[j] = (short)f2bf(WgF[(k0 + j) * D + c]);
        fp[j] = (short)f2bf(WpF[(k0 + j) * D + c]);
      }
    } else {
      const ushort* WgH = (const ushort*)Wg;
      const ushort* WpH = (const ushort*)Wp;
#pragma unroll
      for (int j = 0; j < 8; ++j) {
        fg[j] = (short)WgH[(k0 + j) * D + c];
        fp[j] = (short)WpH[(k0 + j) * D + c];
      }
    }
    bG[kt] = fg;
    bP[kt] = fp;
  }
  float btc;
  {
    float a = isf ? ((const float*)bg)[c] : bf2f(((const ushort*)bg)[c]);
    float b = isf ? ((const float*)bp)[c] : bf2f(((const ushort*)bp)[c]);
    btc = a + b + 1e-6f;
  }

  for (int row0 = blockIdx.x * 64; row0 < M; row0 += gridDim.x * 64) {
    for (int u = tid; u < 1024; u += 512) {
      int row = u >> 4, kc = u & 15;
      int grow = row0 + row;
      uint4 hi = make_uint4(0, 0, 0, 0), lo = make_uint4(0, 0, 0, 0);
      if (isf) {
        if (grow < M) {
          const float4* Xf = (const float4*)X;
          float4 v0 = Xf[(size_t)grow * 32 + kc * 2];
          float4 v1 = Xf[(size_t)grow * 32 + kc * 2 + 1];
          float v[8] = {v0.x, v0.y, v0.z, v0.w, v1.x, v1.y, v1.z, v1.w};
          uint hw[4], lw[4];
#pragma unroll
          for (int j = 0; j < 4; ++j) {
            ushort h0 = f2bf(v[2 * j]), h1 = f2bf(v[2 * j + 1]);
            ushort l0 = f2bf(v[2 * j] - bf2f(h0));
            ushort l1 = f2bf(v[2 * j + 1] - bf2f(h1));
            hw[j] = (uint)h0 | ((uint)h1 << 16);
            lw[j] = (uint)l0 | ((uint)l1 << 16);
          }
          hi = make_uint4(hw[0], hw[1], hw[2], hw[3]);
          lo = make_uint4(lw[0], lw[1], lw[2], lw[3]);
        }
      } else {
        if (grow < M) hi = ((const uint4*)X)[(size_t)grow * 16 + kc];
      }
      int ln = (kc & 3) * 16 + (row & 15);
      int g = row >> 4, kt = kc >> 2;
      aF[g][kt][0][ln] = hi;
      if (isf) aF[g][kt][1][ln] = lo;
    }
    __syncthreads();

#pragma unroll
    for (int g = 0; g < 4; ++g) {
      f32x4 accG = {0.f, 0.f, 0.f, 0.f};
      f32x4 accP = {0.f, 0.f, 0.f, 0.f};
      uint4 aH[4];
#pragma unroll
      for (int kt = 0; kt < 4; ++kt) aH[kt] = aF[g][kt][0][lane];
#pragma unroll
      for (int kt = 0; kt < 4; ++kt) {
        short8 a = __builtin_bit_cast(short8, aH[kt]);
        accG = __builtin_amdgcn_mfma_f32_16x16x32_bf16(a, bG[kt], accG, 0, 0, 0);
        accP = __builtin_amdgcn_mfma_f32_16x16x32_bf16(a, bP[kt], accP, 0, 0, 0);
      }
      if (isf) {
        uint4 aL[4];
#pragma unroll
        for (int kt = 0; kt < 4; ++kt) aL[kt] = aF[g][kt][1][lane];
#pragma unroll
        for (int kt = 0; kt < 4; ++kt) {
          short8 a = __builtin_bit_cast(short8, aL[kt]);
          accG = __builtin_amdgcn_mfma_f32_16x16x32_bf16(a, bG[kt], accG, 0, 0, 0);
          accP = __builtin_amdgcn_mfma_f32_16x16x32_bf16(a, bP[kt], accP, 0, 0, 0);
        }
      }
      int rl0 = g * 16 + kg * 4;
#pragma unroll
      for (int r = 0; r < 4; ++r) {
        int row = row0 + rl0 + r;
        if (row < M) {
          float dn = dinv[row];
          float gv = accG[r], pv = accP[r];
          xwl[rl0 + r][c] = f2bf(gv * dn);
          float ov = fmaf(gv, dn * dn, pv + btc);
          if (isf)
            ((float*)outx3)[(size_t)row * D + c] = ov;
          else
            ((ushort*)outx3)[(size_t)row * D + c] = f2bf(ov);
        }
      }
    }
    __syncthreads();

    int valid = min(64, M - row0);
    const uint4* src = (const uint4*)xwl;
    uint4* dst = (uint4*)xw2 + (size_t)row0 * 16;
    for (int u = tid; u < valid * 16; u += 512) dst[u] = src[u];
  }
}

// ---------------------------------------------------------------------------
// MFMA drug GEMM: yd2[M][64] bf16 pairs = x_drug @ W_td + b_td
// ---------------------------------------------------------------------------
__global__ __launch_bounds__(512) void gemm_drug_mfma(
    const void* __restrict__ X, const void* __restrict__ W,
    const void* __restrict__ bias, uint* __restrict__ Y2,
    const int* __restrict__ flag, int M) {
  __shared__ uint4 aF[4][4][2][64];  // 32 KB
  __shared__ ushort yl[64][128];     // 16 KB
  const int isf = *flag;
  const int tid = threadIdx.x;
  const int wv = tid >> 6, lane = tid & 63;
  const int cl = lane & 15, kg = lane >> 4;
  const int c = wv * 16 + cl;

  short8 bT[4];
#pragma unroll
  for (int kt = 0; kt < 4; ++kt) {
    int k0 = kt * 32 + 8 * kg;
    short8 ft;
    if (isf) {
      const float* Wf = (const float*)W;
#pragma unroll
      for (int j = 0; j < 8; ++j) ft[j] = (short)f2bf(Wf[(k0 + j) * D + c]);
    } else {
      const ushort* Wh = (const ushort*)W;
#pragma unroll
      for (int j = 0; j < 8; ++j) ft[j] = (short)Wh[(k0 + j) * D + c];
    }
    bT[kt] = ft;
  }
  float btc = isf ? ((const float*)bias)[c] : bf2f(((const ushort*)bias)[c]);

  for (int row0 = blockIdx.x * 64; row0 < M; row0 += gridDim.x * 64) {
    for (int u = tid; u < 1024; u += 512) {
      int row = u >> 4, kc = u & 15;
      int grow = row0 + row;
      uint4 hi = make_uint4(0, 0, 0, 0), lo = make_uint4(0, 0, 0, 0);
      if (isf) {
        if (grow < M) {
          const float4* Xf = (const float4*)X;
          float4 v0 = Xf[(size_t)grow * 32 + kc * 2];
          float4 v1 = Xf[(size_t)grow * 32 + kc * 2 + 1];
          float v[8] = {v0.x, v0.y, v0.z, v0.w, v1.x, v1.y, v1.z, v1.w};
          uint hw[4], lw[4];
#pragma unroll
          for (int j = 0; j < 4; ++j) {
            ushort h0 = f2bf(v[2 * j]), h1 = f2bf(v[2 * j + 1]);
            ushort l0 = f2bf(v[2 * j] - bf2f(h0));
            ushort l1 = f2bf(v[2 * j + 1] - bf2f(h1));
            hw[j] = (uint)h0 | ((uint)h1 << 16);
            lw[j] = (uint)l0 | ((uint)l1 << 16);
          }
          hi = make_uint4(hw[0], hw[1], hw[2], hw[3]);
          lo = make_uint4(lw[0], lw[1], lw[2], lw[3]);
        }
      } else {
        if (grow < M) hi = ((const uint4*)X)[(size_t)grow * 16 + kc];
      }
      int ln = (kc & 3) * 16 + (row & 15);
      int g = row >> 4, kt = kc >> 2;
      aF[g][kt][0][ln] = hi;
      if (isf) aF[g][kt][1][ln] = lo;
    }
    __syncthreads();

#pragma unroll
    for (int g = 0; g < 4; ++g) {
      f32x4 acc = {0.f, 0.f, 0.f, 0.f};
      uint4 aH[4];
#pragma unroll
      for (int kt = 0; kt < 4; ++kt) aH[kt] = aF[g][kt][0][lane];
#pragma unroll
      for (int kt = 0; kt < 4; ++kt) {
        short8 a = __builtin_bit_cast(short8, aH[kt]);
        acc = __builtin_amdgcn_mfma_f32_16x16x32_bf16(a, bT[kt], acc, 0, 0, 0);
      }
      if (isf) {
        uint4 aL[4];
#pragma unroll
        for (int kt = 0; kt < 4; ++kt) aL[kt] = aF[g][kt][1][lane];
#pragma unroll
        for (int kt = 0; kt < 4; ++kt) {
          short8 a = __builtin_bit_cast(short8, aL[kt]);
          acc = __builtin_amdgcn_mfma_f32_16x16x32_bf16(a, bT[kt], acc, 0, 0, 0);
        }
      }
      int rl0 = g * 16 + kg * 4;
#pragma unroll
      for (int r = 0; r < 4; ++r) {
        int row = row0 + rl0 + r;
        if (row < M) yl[rl0 + r][c] = f2bf(acc[r] + btc);
      }
    }
    __syncthreads();

    int valid = min(64, M - row0);
    const uint4* src = (const uint4*)yl;
    uint4* dst = (uint4*)Y2 + (size_t)row0 * 16;
    for (int u = tid; u < valid * 16; u += 512) dst[u] = src[u];
  }
}

// ---------------------------------------------------------------------------
// Pure gather + LayerNorm. One wave per node.
// ---------------------------------------------------------------------------
__global__ __launch_bounds__(256) void gather_ln_kernel(
    const uint* __restrict__ xw2, const uint* __restrict__ yd2,
    const float* __restrict__ dinv, const float* __restrict__ invcnt,
    const int* __restrict__ offsets, const int* __restrict__ deg,
    const uint* __restrict__ csr, void* __restrict__ out,
    const int* __restrict__ flag, int n_prot) {
  int isf = *flag;
  int node = (blockIdx.x * 256 + threadIdx.x) >> 6;
  int j2 = threadIdx.x & 63;
  if (node >= n_prot) return;
  int s0 = offsets[node];
  int s1 = offsets[node + 1];
  int sm = s0 + deg[node];
  float dn = dinv[node], ic = invcnt[node];

  float apx = 0.f, apy = 0.f;  // PPI sum (rows pre-scaled by dinv[src])
  for (int base = s0; base < sm;) {
    int m = min(64, sm - base);
    uint ent = (j2 < m) ? csr[base + j2] : 0u;
    int j = 0;
    for (; j + 8 <= m; j += 8) {
      uint e0 = __shfl(ent, j), e1 = __shfl(ent, j + 1);
      uint e2 = __shfl(ent, j + 2), e3 = __shfl(ent, j + 3);
      uint e4 = __shfl(ent, j + 4), e5 = __shfl(ent, j + 5);
      uint e6 = __shfl(ent, j + 6), e7 = __shfl(ent, j + 7);
      float2 v0 = bf16x2(xw2[(size_t)e0 * 64 + j2]);
      float2 v1 = bf16x2(xw2[(size_t)e1 * 64 + j2]);
      float2 v2 = bf16x2(xw2[(size_t)e2 * 64 + j2]);
      float2 v3 = bf16x2(xw2[(size_t)e3 * 64 + j2]);
      float2 v4 = bf16x2(xw2[(size_t)e4 * 64 + j2]);
      float2 v5 = bf16x2(xw2[(size_t)e5 * 64 + j2]);
      float2 v6 = bf16x2(xw2[(size_t)e6 * 64 + j2]);
      float2 v7 = bf16x2(xw2[(size_t)e7 * 64 + j2]);
      apx += ((v0.x + v1.x) + (v2.x + v3.x)) + ((v4.x + v5.x) + (v6.x + v7.x));
      apy += ((v0.y + v1.y) + (v2.y + v3.y)) + ((v4.y + v5.y) + (v6.y + v7.y));
    }
    for (; j + 2 <= m; j += 2) {
      uint e0 = __shfl(ent, j), e1 = __shfl(ent, j + 1);
      float2 v0 = bf16x2(xw2[(size_t)e0 * 64 + j2]);
      float2 v1 = bf16x2(xw2[(size_t)e1 * 64 + j2]);
      apx += v0.x + v1.x;
      apy += v0.y + v1.y;
    }
    for (; j < m; ++j) {
      uint e = __shfl(ent, j);
      float2 v = bf16x2(xw2[(size_t)e * 64 + j2]);
      apx += v.x;
      apy += v.y;
    }
    base += m;
  }

  float adx = 0.f, ady = 0.f;  // DTI sum
  for (int base = sm; base < s1;) {
    int m = min(64, s1 - base);
    uint ent = (j2 < m) ? csr[base + j2] : 0u;
    int j = 0;
    for (; j + 8 <= m; j += 8) {
      uint e0 = __shfl(ent, j), e1 = __shfl(ent, j + 1);
      uint e2 = __shfl(ent, j + 2), e3 = __shfl(ent, j + 3);
      uint e4 = __shfl(ent, j + 4), e5 = __shfl(ent, j + 5);
      uint e6 = __shfl(ent, j + 6), e7 = __shfl(ent, j + 7);
      float2 v0 = bf16x2(yd2[(size_t)e0 * 64 + j2]);
      float2 v1 = bf16x2(yd2[(size_t)e1 * 64 + j2]);
      float2 v2 = bf16x2(yd2[(size_t)e2 * 64 + j2]);
      float2 v3 = bf16x2(yd2[(size_t)e3 * 64 + j2]);
      float2 v4 = bf16x2(yd2[(size_t)e4 * 64 + j2]);
      float2 v5 = bf16x2(yd2[(size_t)e5 * 64 + j2]);
      float2 v6 = bf16x2(yd2[(size_t)e6 * 64 + j2]);
      float2 v7 = bf16x2(yd2[(size_t)e7 * 64 + j2]);
      adx += ((v0.x + v1.x) + (v2.x + v3.x)) + ((v4.x + v5.x) + (v6.x + v7.x));
      ady += ((v0.y + v1.y) + (v2.y + v3.y)) + ((v4.y + v5.y) + (v6.y + v7.y));
    }
    for (; j + 2 <= m; j += 2) {
      uint e0 = __shfl(ent, j), e1 = __shfl(ent, j + 1);
      float2 v0 = bf16x2(yd2[(size_t)e0 * 64 + j2]);
      float2 v1 = bf16x2(yd2[(size_t)e1 * 64 + j2]);
      adx += v0.x + v1.x;
      ady += v0.y + v1.y;
    }
    for (; j < m; ++j) {
      uint e = __shfl(ent, j);
      float2 v = bf16x2(yd2[(size_t)e * 64 + j2]);
      adx += v.x;
      ady += v.y;
    }
    base += m;
  }

  float2 x3v;
  if (isf)
    x3v = ((const float2*)out)[(size_t)node * 64 + j2];
  else
    x3v = bf16x2(((const uint*)out)[(size_t)node * 64 + j2]);
  float v0 = fmaf(dn, apx, fmaf(ic, adx, x3v.x));
  float v1 = fmaf(dn, apy, fmaf(ic, ady, x3v.y));

  float s = v0 + v1, ss = v0 * v0 + v1 * v1;
  for (int off = 1; off < 64; off <<= 1) {
    s += __shfl_xor(s, off);
    ss += __shfl_xor(ss, off);
  }
  float mu = s * (1.0f / 128.0f);
  float var = ss * (1.0f / 128.0f) - mu * mu;
  float rs = rsqrtf(var + 1e-5f);
  float o0 = (v0 - mu) * rs, o1 = (v1 - mu) * rs;
  if (isf)
    ((float2*)out)[(size_t)node * 64 + j2] = make_float2(o0, o1);
  else
    ((uint*)out)[(size_t)node * 64 + j2] = pack_bf16x2(o0, o1);
}

// ---------------------------------------------------------------------------
extern "C" void kernel_launch(void* const* d_in, const int* in_sizes, int n_in,
                              void* d_out, int out_size, void* d_ws,
                              size_t ws_size, hipStream_t stream) {
  const void* x_prot = d_in[0];
  const void* x_drug = d_in[1];
  const void* W_gcn = d_in[2];
  const void* b_gcn = d_in[3];
  const void* W_td = d_in[4];
  const void* b_td = d_in[5];
  const void* W_pr = d_in[6];
  const void* b_pr = d_in[7];
  const int* ppi = (const int*)d_in[8];
  const int* dti_drug = (const int*)d_in[9];
  const int* dti_prot = (const int*)d_in[10];

  int n_prot = in_sizes[0] / D;
  int n_drug = in_sizes[1] / D;
  int e_ppi = in_sizes[8] / 2;
  int e_dti = in_sizes[9];
  int e_tot = e_ppi + e_dti;
  int nb = (n_prot + 255) / 256;
  int nbk = (n_prot + NPBK - 1) / NPBK;  // coarse buckets

  char* ws = (char*)d_ws;
  size_t off = 0;
  auto alloc = [&](size_t bytes) {
    void* p = ws + off;
    off = (off + bytes + 255) & ~(size_t)255;
    return p;
  };
  int* flag = (int*)alloc(256);
  uint* xw2 = (uint*)alloc((size_t)n_prot * 64 * 4);  // 25.6 MB (pre-scaled)
  uint* yd2 = (uint*)alloc((size_t)n_drug * 64 * 4);  //  5.1 MB
  int* deg = (int*)alloc((size_t)n_prot * 4);
  int* cnt = (int*)alloc((size_t)n_prot * 4);
  float* dinv = (float*)alloc((size_t)n_prot * 4);
  float* invcnt = (float*)alloc((size_t)n_prot * 4);
  int* offsets = (int*)alloc((size_t)(n_prot + 1) * 4);
  int* fposp = (int*)alloc((size_t)n_prot * 4);
  int* fposd = (int*)alloc((size_t)n_prot * 4);
  int* bsum = (int*)alloc((size_t)nb * 4);
  int* bcur = (int*)alloc((size_t)nbk * 4);
  uint* csr = (uint*)alloc((size_t)e_tot * 4);  // 9.6 MB

  if (off > ws_size) return;  // insufficient workspace: bail cleanly

  // Partitioned-edge scratch aliases xw2: place_kernel finishes before
  // gemm_prot_mfma writes xw2 (same stream), and e_tot*4 <= n_prot*256 here.
  uint* P = xw2;
  bool fast_fill = (n_prot <= (1 << 17)) && (n_drug <= (1 << 17)) &&
                   (nbk <= NBMAX) && ((size_t)e_tot * 4 <= (size_t)n_prot * 256);

  detect_kernel<<<1, 256, 0, stream>>>((const uint*)x_prot, 4096, flag);

  hipMemsetAsync(deg, 0, (size_t)n_prot * 4, stream);
  hipMemsetAsync(cnt, 0, (size_t)n_prot * 4, stream);

  count_kernel<<<(e_tot + 255) / 256, 256, 0, stream>>>(
      ppi + e_ppi, dti_prot, deg, cnt, e_ppi, e_dti, n_prot);

  block_sum_kernel<<<nb, 256, 0, stream>>>(deg, cnt, n_prot, dinv, invcnt,
                                           bsum);
  scan_bsums_kernel<<<1, 1024, 0, stream>>>(bsum, nb);
  scan_final_kernel<<<nb, 256, 0, stream>>>(deg, cnt, bsum, offsets, n_prot);

  if (fast_fill) {
    bcur_init_kernel<<<(nbk + 255) / 256, 256, 0, stream>>>(offsets, bcur, nbk,
                                                            n_prot);
    partition_kernel<<<(e_tot + TILE_A - 1) / TILE_A, 256, 0, stream>>>(
        ppi, ppi + e_ppi, dti_drug, dti_prot, bcur, P, e_ppi, e_dti, n_prot,
        nbk);
    place_kernel<<<nbk, 256, 0, stream>>>(P, offsets, deg, csr, n_prot);
  } else {
    hipMemsetAsync(fposp, 0, (size_t)n_prot * 4, stream);
    hipMemsetAsync(fposd, 0, (size_t)n_prot * 4, stream);
    fill_kernel<<<(e_tot + 255) / 256, 256, 0, stream>>>(
        ppi, ppi + e_ppi, dti_drug, dti_prot, offsets, deg, fposp, fposd, csr,
        e_ppi, e_dti, n_prot);
  }

  int nbat_p = (n_prot + 63) / 64;
  int grid_p = nbat_p < 512 ? nbat_p : 512;
  gemm_prot_mfma<<<grid_p, 512, 0, stream>>>(x_prot, W_gcn, W_pr, b_gcn, b_pr,
                                             dinv, xw2, d_out, flag, n_prot);
  int nbat_d = (n_drug + 63) / 64;
  int grid_d = nbat_d < 512 ? nbat_d : 512;
  gemm_drug_mfma<<<grid_d, 512, 0, stream>>>(x_drug, W_td, b_td, yd2, flag,
                                             n_drug);

  gather_ln_kernel<<<(n_prot + 3) / 4, 256, 0, stream>>>(
      xw2, yd2, dinv, invcnt, offsets, deg, csr, d_out, flag, n_prot);
}